// Round 10
// baseline (946.885 us; speedup 1.0000x reference)
//
#include <hip/hip_runtime.h>

#define NP 32
#define NROWS 65536

typedef _Float16 f16x8 __attribute__((ext_vector_type(8)));
typedef _Float16 f16x4 __attribute__((ext_vector_type(4)));
typedef _Float16 f16x2 __attribute__((ext_vector_type(2)));
typedef float    f32x4 __attribute__((ext_vector_type(4)));

#define FAST_RCP(x) __builtin_amdgcn_rcpf(x)

// tanh(x) = 1 - 2/(e^{2x}+1); saturates correctly at +-inf, no clamp needed.
__device__ __forceinline__ float fast_tanh(float v) {
    float e = __expf(2.0f * v);
    return fmaf(-2.0f, FAST_RCP(e + 1.0f), 1.0f);
}

__device__ __forceinline__ f16x4 pack4(float c0, float c1, float c2, float c3) {
    const f16x2 p01 = __builtin_bit_cast(f16x2, __builtin_amdgcn_cvt_pkrtz(c0, c1));
    const f16x2 p23 = __builtin_bit_cast(f16x2, __builtin_amdgcn_cvt_pkrtz(c2, c3));
    return __builtin_shufflevector(p01, p23, 0, 1, 2, 3);
}
__device__ __forceinline__ f16x8 cat8(f16x4 a, f16x4 b) {
    return __builtin_shufflevector(a, b, 0, 1, 2, 3, 4, 5, 6, 7);
}
__device__ __forceinline__ f16x4 tanh_pack(f32x4 a) {
    return pack4(fast_tanh(a[0]), fast_tanh(a[1]), fast_tanh(a[2]), fast_tanh(a[3]));
}
__device__ __forceinline__ f16x4 relu_pack(f32x4 a) {
    return pack4(fmaxf(a[0], 0.f), fmaxf(a[1], 0.f), fmaxf(a[2], 0.f), fmaxf(a[3], 0.f));
}
__device__ __forceinline__ f32x4 tanh4(f32x4 a) {
    return f32x4{fast_tanh(a[0]), fast_tanh(a[1]), fast_tanh(a[2]), fast_tanh(a[3])};
}

// ---- virtual-channel maps: channel consumed at layer-k slot k --------------
// C slot r=16Mt+4g+j forwards (identity, in-register) to B slot k:
//   32-wide: k = 8g+4Mt+j      -> col32(k) inverts
//   64-wide: k = 32(Mt>>1)+8g+4(Mt&1)+j -> col64(k)
//   16-wide (A3->A4 via shfl_xor32): col16 = swap bits 2,3
__device__ __forceinline__ int col64(int k) {
    return 32 * (k >> 5) + 16 * ((k >> 2) & 1) + (((k >> 3) & 3) << 2) + (k & 3);
}
__device__ __forceinline__ int col32(int k) {
    return 16 * ((k >> 2) & 1) + ((k >> 3) << 2) + (k & 3);
}
__device__ __forceinline__ int col16(int k) {
    return (k & 3) | ((k >> 1) & 4) | ((k & 4) << 1);
}

// ---------------- prepacked weight storage (device globals) ----------------
// 17 MFMA steps: B1:s0-3 (bias in k=31 col) B2:s4-7 B3:s8-9 B4:s10
//                A2:s11-14 A3:s15 A4:s16 (order: Mt, ks)
// A-frag: row=lane&15 (=out), k=8*(l>>4)+e; columns pre-permuted per col maps.
// bias steps (C-layout out=16bMt+4g+j): B2:0-1 B3:2-3 B4:4 A2:5-6 A3:7 A4:8
__device__ __align__(16) _Float16 g_frag[NP][17 * 2 * 64 * 8]; // hi/lo pairs
__device__ __align__(16) float    g_bias[NP][9 * 64 * 4];
__device__ __align__(16) float    g_a1w [NP][64 * 16];  // A1 in B-slot order
__device__ __align__(16) float    g_a1b [NP][64 * 16];
// fin: [0..15]=W56 (Wb6·Wb5), [16..31]=Wa5 zero-padded, [32]=b56, [33]=ba5
__device__ __align__(16) float    g_fin [NP][36];

__global__ void prep_frags(
    const float* __restrict__ Wa1, const float* __restrict__ ba1,
    const float* __restrict__ Wa2, const float* __restrict__ ba2,
    const float* __restrict__ Wa3, const float* __restrict__ ba3,
    const float* __restrict__ Wa4, const float* __restrict__ ba4,
    const float* __restrict__ Wa5, const float* __restrict__ ba5,
    const float* __restrict__ Wb1, const float* __restrict__ bb1,
    const float* __restrict__ Wb2, const float* __restrict__ bb2,
    const float* __restrict__ Wb3, const float* __restrict__ bb3,
    const float* __restrict__ Wb4, const float* __restrict__ bb4,
    const float* __restrict__ Wb5, const float* __restrict__ bb5,
    const float* __restrict__ Wb6, const float* __restrict__ bb6) {
    const int p = blockIdx.x;
    const int l = threadIdx.x;          // 0..63
    const int g = l >> 4, q = l & 15;

    const int sw[17]  = {0,0,0,0, 1,1,1,1, 2,2, 3, 4,4,4,4, 5, 6};
    const int sMt[17] = {0,1,2,3, 0,0,1,1, 0,1, 0, 0,0,1,1, 0, 0};
    const int sks[17] = {0,0,0,0, 0,1,0,1, 0,0, 0, 0,1,0,1, 0, 0};
    const int OO[7] = {64,32,32,16,32,16, 8};
    const int II[7] = {31,64,32,32,64,32,16};
    const float* WS[7] = {Wb1 + p*1984, Wb2 + p*2048, Wb3 + p*1024,
                          Wb4 + p*512,  Wa2 + p*2048, Wa3 + p*512,
                          Wa4 + p*128};
    const float* b1s = bb1 + p*64;
    for (int s = 0; s < 17; ++s) {
        const int w = sw[s], O = OO[w], I = II[w];
        const float* W = WS[w];
        for (int e = 0; e < 8; ++e) {
            const int kk = 32*sks[s] + 8*g + e;   // layer-k slot
            const int o  = 16*sMt[s] + q;         // out (= A row)
            float wv = 0.0f;
            if (o < O) {
                if (s < 4) {        // B1: direct x order; col 31 = bias
                    wv = (kk < 31) ? W[o*31 + kk] : (kk == 31 ? b1s[o] : 0.0f);
                } else if (w == 1 || w == 4) {          // 64-wide input
                    wv = W[o*I + col64(kk)];
                } else if (w == 6) {                    // A4: 16-wide input
                    wv = (kk < 16) ? W[o*I + col16(kk)] : 0.0f;
                } else {                                // 32-wide input
                    wv = W[o*I + col32(kk)];
                }
            }
            const _Float16 hi = (_Float16)wv;
            const _Float16 lo = (_Float16)(wv - (float)hi);
            g_frag[p][((s*2 + 0)*64 + l)*8 + e] = hi;
            g_frag[p][((s*2 + 1)*64 + l)*8 + e] = lo;
        }
    }
    const int bw[9]  = {0,0, 1,1, 2, 3,3, 4, 5};
    const int bMt[9] = {0,1, 0,1, 0, 0,1, 0, 0};
    const float* BS[6] = {bb2 + p*32, bb3 + p*32, bb4 + p*16,
                          ba2 + p*32, ba3 + p*16, ba4 + p*8};
    const int BO[6] = {32,32,16,32,16,8};
    for (int bs = 0; bs < 9; ++bs) {
        const int w = bw[bs];
        for (int j = 0; j < 4; ++j) {
            const int o = 16*bMt[bs] + 4*g + j;
            g_bias[p][(bs*64 + l)*4 + j] = (o < BO[w]) ? BS[w][o] : 0.0f;
        }
    }
    // A1 weights directly in B-slot order (out channel = col64 of slot)
    for (int idx = 0; idx < 16; ++idx) {
        const int ks = idx >> 3, e = idx & 7;
        const int c = col64(32*ks + 8*g + e);
        g_a1w[p][l*16 + idx] = Wa1[p*64 + c];
        g_a1b[p][l*16 + idx] = ba1[p*64 + c];
    }
    if (l == 0) {
        // fold B5 (16->8) and B6 (8->1): W56 = Wb6·Wb5, b56 = Wb6·bb5 + bb6
        for (int i = 0; i < 16; ++i) {
            float s = 0.0f;
            for (int o = 0; o < 8; ++o)
                s += Wb6[p*8 + o] * Wb5[p*128 + o*16 + i];
            g_fin[p][i] = s;
        }
        for (int i = 0; i < 16; ++i)
            g_fin[p][16 + i] = (i < 8) ? Wa5[p*8 + i] : 0.0f;
        float s = bb6[p];
        for (int o = 0; o < 8; ++o) s += Wb6[p*8 + o] * bb5[p*8 + o];
        g_fin[p][32] = s;
        g_fin[p][33] = ba5[p];
    }
}

// ---------------- main kernel: ZERO LDS, all forwarding in registers -------
__device__ __forceinline__ f32x4 mfma2(const _Float16* __restrict__ frag,
                                       int s, int l, f16x8 b, f32x4 acc) {
    const f16x8 wlo = *(const f16x8*)(frag + ((s*2 + 1)*64 + l)*8);
    const f16x8 whi = *(const f16x8*)(frag + ((s*2 + 0)*64 + l)*8);
    acc = __builtin_amdgcn_mfma_f32_16x16x32_f16(wlo, b, acc, 0, 0, 0);
    acc = __builtin_amdgcn_mfma_f32_16x16x32_f16(whi, b, acc, 0, 0, 0);
    return acc;
}

#define BIAS4(bs) (*(const f32x4*)(bias + ((bs)*64 + l)*4))

__global__ __launch_bounds__(256, 4) void mlp_mfma(
    const float* __restrict__ x, float* __restrict__ out) {
    // Block remap: 32 p-blocks of one row chunk consecutive on one XCD so
    // partial 8B output writes merge in L2 (verified r7: 162 -> 16.4 MB).
    const int L   = blockIdx.x;          // 0..16383
    const int xcd = L & 7;
    const int m   = L >> 3;
    const int p   = m & 31;              // feature
    const int rc  = xcd + 8 * (m >> 5);  // row chunk 0..511
    const int wv  = threadIdx.x >> 6;
    const int l   = threadIdx.x & 63;
    const int g   = l >> 4, q = l & 15;
    const int row0 = rc * 128 + wv * 32;

    const _Float16* frag = g_frag[p];
    const float*    bias = g_bias[p];
    const float*    fin  = g_fin[p];
    const f32x4 finB = *(const f32x4*)(fin + 4*g);
    const f32x4 finA = *(const f32x4*)(fin + 16 + 4*g);
    const float b56 = fin[32], ba5v = fin[33];
    const f32x4* a1w = (const f32x4*)(g_a1w[p] + l*16);
    const f32x4* a1b = (const f32x4*)(g_a1b[p] + l*16);

#pragma unroll
    for (int t = 0; t < 2; ++t) {
        const int grow = row0 + 16*t + q;
        const float* xr = x + grow * NP;
        // B1 operand: leave-one-out x, k=31 slot = 1.0 (bias column)
        f16x8 bX;
#pragma unroll
        for (int e = 0; e < 8; ++e) {
            const int k = 8*g + e;
            bX[e] = (_Float16)((k < 31) ? xr[k + (k >= p)] : 1.0f);
        }
        const float xa = xr[p];

        // ---- B chain -------------------------------------------------------
        f16x4 h0, h1, h2, h3;
        { f32x4 a{0,0,0,0}; a = mfma2(frag, 0, l, bX, a); h0 = relu_pack(a); }
        { f32x4 a{0,0,0,0}; a = mfma2(frag, 1, l, bX, a); h1 = relu_pack(a); }
        { f32x4 a{0,0,0,0}; a = mfma2(frag, 2, l, bX, a); h2 = relu_pack(a); }
        { f32x4 a{0,0,0,0}; a = mfma2(frag, 3, l, bX, a); h3 = relu_pack(a); }
        const f16x8 bk0 = cat8(h0, h1), bk1 = cat8(h2, h3);  // B1 out (64)

        f16x4 u0, u1;
        { f32x4 a = BIAS4(0); a = mfma2(frag, 4, l, bk0, a);
          a = mfma2(frag, 5, l, bk1, a); u0 = tanh_pack(a); }
        { f32x4 a = BIAS4(1); a = mfma2(frag, 6, l, bk0, a);
          a = mfma2(frag, 7, l, bk1, a); u1 = tanh_pack(a); }
        const f16x8 b2 = cat8(u0, u1);                        // B2 out (32)

        { f32x4 a = BIAS4(2); a = mfma2(frag, 8, l, b2, a); u0 = tanh_pack(a); }
        { f32x4 a = BIAS4(3); a = mfma2(frag, 9, l, b2, a); u1 = tanh_pack(a); }
        const f16x8 b3 = cat8(u0, u1);                        // B3 out (32)

        float bv;
        { f32x4 a = BIAS4(4); a = mfma2(frag, 10, l, b3, a);  // B4 out (16)
          const f32x4 c = tanh4(a);
          float s =            finB[0] * c[0];
          s = fmaf(finB[1], c[1], s);
          s = fmaf(finB[2], c[2], s);
          s = fmaf(finB[3], c[3], s);
          s += __shfl_xor(s, 16);
          s += __shfl_xor(s, 32);
          bv = s + b56; }

        // ---- A chain -------------------------------------------------------
        f16x8 bA[2];                                          // A1 out (64)
#pragma unroll
        for (int ks = 0; ks < 2; ++ks) {
            const f32x4 w0 = a1w[2*ks], v0 = a1b[2*ks];
            const f32x4 w1 = a1w[2*ks + 1], v1 = a1b[2*ks + 1];
            float c0[4], c1[4];
#pragma unroll
            for (int j = 0; j < 4; ++j) {
                c0[j] = fmaxf(fmaf(w0[j], xa, v0[j]), 0.f);
                c1[j] = fmaxf(fmaf(w1[j], xa, v1[j]), 0.f);
            }
            bA[ks] = cat8(pack4(c0[0], c0[1], c0[2], c0[3]),
                          pack4(c1[0], c1[1], c1[2], c1[3]));
        }

        { f32x4 a = BIAS4(5); a = mfma2(frag, 11, l, bA[0], a);
          a = mfma2(frag, 12, l, bA[1], a); u0 = tanh_pack(a); }
        { f32x4 a = BIAS4(6); a = mfma2(frag, 13, l, bA[0], a);
          a = mfma2(frag, 14, l, bA[1], a); u1 = tanh_pack(a); }
        const f16x8 a2 = cat8(u0, u1);                        // A2 out (32)

        f16x8 a3f;
        { f32x4 a = BIAS4(7); a = mfma2(frag, 15, l, a2, a);  // A3 out (16)
          const f16x4 own = tanh_pack(a);
          const float2 ow = __builtin_bit_cast(float2, own);
          float2 pw;
          pw.x = __shfl_xor(ow.x, 32);
          pw.y = __shfl_xor(ow.y, 32);
          a3f = cat8(own, __builtin_bit_cast(f16x4, pw)); }   // xor32 halves

        float av;
        { f32x4 a = BIAS4(8); a = mfma2(frag, 16, l, a3f, a); // A4 out (8)
          const f32x4 c = tanh4(a);
          float s =            finA[0] * c[0];
          s = fmaf(finA[1], c[1], s);
          s = fmaf(finA[2], c[2], s);
          s = fmaf(finA[3], c[3], s);
          s += __shfl_xor(s, 16);
          s += __shfl_xor(s, 32);
          av = s + ba5v; }

        if (g == 0) {
            reinterpret_cast<float2*>(out)[(size_t)grow * NP + p] =
                make_float2(av, bv);
        }
    }
}

extern "C" void kernel_launch(void* const* d_in, const int* in_sizes, int n_in,
                              void* d_out, int out_size, void* d_ws,
                              size_t ws_size, hipStream_t stream) {
    const float* x   = (const float*)d_in[0];
    const float* Wa1 = (const float*)d_in[1];
    const float* ba1 = (const float*)d_in[2];
    const float* Wa2 = (const float*)d_in[3];
    const float* ba2 = (const float*)d_in[4];
    const float* Wa3 = (const float*)d_in[5];
    const float* ba3 = (const float*)d_in[6];
    const float* Wa4 = (const float*)d_in[7];
    const float* ba4 = (const float*)d_in[8];
    const float* Wa5 = (const float*)d_in[9];
    const float* ba5 = (const float*)d_in[10];
    const float* Wb1 = (const float*)d_in[11];
    const float* bb1 = (const float*)d_in[12];
    const float* Wb2 = (const float*)d_in[13];
    const float* bb2 = (const float*)d_in[14];
    const float* Wb3 = (const float*)d_in[15];
    const float* bb3 = (const float*)d_in[16];
    const float* Wb4 = (const float*)d_in[17];
    const float* bb4 = (const float*)d_in[18];
    const float* Wb5 = (const float*)d_in[19];
    const float* bb5 = (const float*)d_in[20];
    const float* Wb6 = (const float*)d_in[21];
    const float* bb6 = (const float*)d_in[22];

    prep_frags<<<dim3(NP), dim3(64), 0, stream>>>(
        Wa1, ba1, Wa2, ba2, Wa3, ba3, Wa4, ba4, Wa5, ba5,
        Wb1, bb1, Wb2, bb2, Wb3, bb3, Wb4, bb4, Wb5, bb5, Wb6, bb6);

    mlp_mfma<<<dim3(NROWS / 128 * NP), 256, 0, stream>>>(x, (float*)d_out);
}

// Round 11
// 283.761 us; speedup vs baseline: 3.3369x; 3.3369x over previous
//
#include <hip/hip_runtime.h>

#define NP 32
#define NROWS 65536

typedef _Float16 f16x8 __attribute__((ext_vector_type(8)));
typedef _Float16 f16x4 __attribute__((ext_vector_type(4)));
typedef _Float16 f16x2 __attribute__((ext_vector_type(2)));
typedef float    f32x4 __attribute__((ext_vector_type(4)));

#define FAST_RCP(x) __builtin_amdgcn_rcpf(x)

// tanh(x) = 1 - 2/(e^{2x}+1); saturates correctly at +-inf, no clamp needed.
__device__ __forceinline__ float fast_tanh(float v) {
    float e = __expf(2.0f * v);
    return fmaf(-2.0f, FAST_RCP(e + 1.0f), 1.0f);
}

__device__ __forceinline__ f16x4 pack4(float c0, float c1, float c2, float c3) {
    const f16x2 p01 = __builtin_bit_cast(f16x2, __builtin_amdgcn_cvt_pkrtz(c0, c1));
    const f16x2 p23 = __builtin_bit_cast(f16x2, __builtin_amdgcn_cvt_pkrtz(c2, c3));
    return __builtin_shufflevector(p01, p23, 0, 1, 2, 3);
}
__device__ __forceinline__ f16x8 cat8(f16x4 a, f16x4 b) {
    return __builtin_shufflevector(a, b, 0, 1, 2, 3, 4, 5, 6, 7);
}
__device__ __forceinline__ f16x4 tanh_pack(f32x4 a) {
    return pack4(fast_tanh(a[0]), fast_tanh(a[1]), fast_tanh(a[2]), fast_tanh(a[3]));
}
__device__ __forceinline__ f16x4 relu_pack(f32x4 a) {
    return pack4(fmaxf(a[0], 0.f), fmaxf(a[1], 0.f), fmaxf(a[2], 0.f), fmaxf(a[3], 0.f));
}
__device__ __forceinline__ f32x4 tanh4(f32x4 a) {
    return f32x4{fast_tanh(a[0]), fast_tanh(a[1]), fast_tanh(a[2]), fast_tanh(a[3])};
}

// ---- virtual-channel maps (verified r9/r10: absmax 0.0039) -----------------
__device__ __forceinline__ int col64(int k) {
    return 32 * (k >> 5) + 16 * ((k >> 2) & 1) + (((k >> 3) & 3) << 2) + (k & 3);
}
__device__ __forceinline__ int col32(int k) {
    return 16 * ((k >> 2) & 1) + ((k >> 3) << 2) + (k & 3);
}
__device__ __forceinline__ int col16(int k) {
    return (k & 3) | ((k >> 1) & 4) | ((k & 4) << 1);
}

// ---------------- prepacked weight storage (device globals) ----------------
// 17 MFMA steps: B1:s0-3 (bias in k=31 col) B2:s4-7 B3:s8-9 B4:s10
//                A2:s11-14 A3:s15 A4:s16 (order: Mt, ks)
// A-frag: row=lane&15 (=out), k=8*(l>>4)+e; columns pre-permuted per col maps.
// bias steps (C-layout out=16bMt+4g+j): B2:0-1 B3:2-3 B4:4 A2:5-6 A3:7 A4:8
__device__ __align__(16) _Float16 g_frag[NP][17 * 2 * 64 * 8]; // hi/lo pairs
__device__ __align__(16) float    g_bias[NP][9 * 64 * 4];
__device__ __align__(16) float    g_a1w [NP][64 * 16];  // A1 in B-slot order
__device__ __align__(16) float    g_a1b [NP][64 * 16];
// fin: [0..15]=W56 (Wb6·Wb5), [16..31]=Wa5 zero-padded, [32]=b56, [33]=ba5
__device__ __align__(16) float    g_fin [NP][36];

__global__ void prep_frags(
    const float* __restrict__ Wa1, const float* __restrict__ ba1,
    const float* __restrict__ Wa2, const float* __restrict__ ba2,
    const float* __restrict__ Wa3, const float* __restrict__ ba3,
    const float* __restrict__ Wa4, const float* __restrict__ ba4,
    const float* __restrict__ Wa5, const float* __restrict__ ba5,
    const float* __restrict__ Wb1, const float* __restrict__ bb1,
    const float* __restrict__ Wb2, const float* __restrict__ bb2,
    const float* __restrict__ Wb3, const float* __restrict__ bb3,
    const float* __restrict__ Wb4, const float* __restrict__ bb4,
    const float* __restrict__ Wb5, const float* __restrict__ bb5,
    const float* __restrict__ Wb6, const float* __restrict__ bb6) {
    const int p = blockIdx.x;
    const int l = threadIdx.x;          // 0..63
    const int g = l >> 4, q = l & 15;

    const int sw[17]  = {0,0,0,0, 1,1,1,1, 2,2, 3, 4,4,4,4, 5, 6};
    const int sMt[17] = {0,1,2,3, 0,0,1,1, 0,1, 0, 0,0,1,1, 0, 0};
    const int sks[17] = {0,0,0,0, 0,1,0,1, 0,0, 0, 0,1,0,1, 0, 0};
    const int OO[7] = {64,32,32,16,32,16, 8};
    const int II[7] = {31,64,32,32,64,32,16};
    const float* WS[7] = {Wb1 + p*1984, Wb2 + p*2048, Wb3 + p*1024,
                          Wb4 + p*512,  Wa2 + p*2048, Wa3 + p*512,
                          Wa4 + p*128};
    const float* b1s = bb1 + p*64;
    for (int s = 0; s < 17; ++s) {
        const int w = sw[s], O = OO[w], I = II[w];
        const float* W = WS[w];
        for (int e = 0; e < 8; ++e) {
            const int kk = 32*sks[s] + 8*g + e;   // layer-k slot
            const int o  = 16*sMt[s] + q;         // out (= A row)
            float wv = 0.0f;
            if (o < O) {
                if (s < 4) {        // B1: direct x order; col 31 = bias
                    wv = (kk < 31) ? W[o*31 + kk] : (kk == 31 ? b1s[o] : 0.0f);
                } else if (w == 1 || w == 4) {          // 64-wide input
                    wv = W[o*I + col64(kk)];
                } else if (w == 6) {                    // A4: 16-wide input
                    wv = (kk < 16) ? W[o*I + col16(kk)] : 0.0f;
                } else {                                // 32-wide input
                    wv = W[o*I + col32(kk)];
                }
            }
            const _Float16 hi = (_Float16)wv;
            const _Float16 lo = (_Float16)(wv - (float)hi);
            g_frag[p][((s*2 + 0)*64 + l)*8 + e] = hi;
            g_frag[p][((s*2 + 1)*64 + l)*8 + e] = lo;
        }
    }
    const int bw[9]  = {0,0, 1,1, 2, 3,3, 4, 5};
    const int bMt[9] = {0,1, 0,1, 0, 0,1, 0, 0};
    const float* BS[6] = {bb2 + p*32, bb3 + p*32, bb4 + p*16,
                          ba2 + p*32, ba3 + p*16, ba4 + p*8};
    const int BO[6] = {32,32,16,32,16,8};
    for (int bs = 0; bs < 9; ++bs) {
        const int w = bw[bs];
        for (int j = 0; j < 4; ++j) {
            const int o = 16*bMt[bs] + 4*g + j;
            g_bias[p][(bs*64 + l)*4 + j] = (o < BO[w]) ? BS[w][o] : 0.0f;
        }
    }
    // A1 weights directly in B-slot order (out channel = col64 of slot)
    for (int idx = 0; idx < 16; ++idx) {
        const int ks = idx >> 3, e = idx & 7;
        const int c = col64(32*ks + 8*g + e);
        g_a1w[p][l*16 + idx] = Wa1[p*64 + c];
        g_a1b[p][l*16 + idx] = ba1[p*64 + c];
    }
    if (l == 0) {
        // fold B5 (16->8) and B6 (8->1): W56 = Wb6·Wb5, b56 = Wb6·bb5 + bb6
        for (int i = 0; i < 16; ++i) {
            float s = 0.0f;
            for (int o = 0; o < 8; ++o)
                s += Wb6[p*8 + o] * Wb5[p*128 + o*16 + i];
            g_fin[p][i] = s;
        }
        for (int i = 0; i < 16; ++i)
            g_fin[p][16 + i] = (i < 8) ? Wa5[p*8 + i] : 0.0f;
        float s = bb6[p];
        for (int o = 0; o < 8; ++o) s += Wb6[p*8 + o] * bb5[p*8 + o];
        g_fin[p][32] = s;
        g_fin[p][33] = ba5[p];
    }
}

// ---------------- main kernel: zero LDS, STEP-MAJOR schedule ---------------
// r10 lesson: per-t serial chains make every weight load t-invariant -> LICM
// hoists ~34 loads (136+ VGPRs) -> RA spill -> 4 GB scratch traffic. Here each
// step's weights are loaded ONCE and immediately consumed by both row-tiles,
// so nothing is hoistable and peak live state ~100 VGPRs.
#define LOADW(s) \
    const f16x8 wlo = *(const f16x8*)(frag + (((s)*2 + 1)*64 + l)*8); \
    const f16x8 whi = *(const f16x8*)(frag + (((s)*2 + 0)*64 + l)*8);
#define MFMA2(bop, acc) \
    acc = __builtin_amdgcn_mfma_f32_16x16x32_f16(wlo, bop, acc, 0, 0, 0); \
    acc = __builtin_amdgcn_mfma_f32_16x16x32_f16(whi, bop, acc, 0, 0, 0);
#define BIAS4(bs) (*(const f32x4*)(bias + ((bs)*64 + l)*4))

__global__ __launch_bounds__(256, 4) void mlp_mfma(
    const float* __restrict__ x, float* __restrict__ out) {
    // Block remap: 32 p-blocks of one row chunk consecutive on one XCD so
    // partial 8B output writes merge in L2 (verified r7: 162 -> 16.4 MB).
    const int L   = blockIdx.x;          // 0..16383
    const int xcd = L & 7;
    const int m   = L >> 3;
    const int p   = m & 31;              // feature
    const int rc  = xcd + 8 * (m >> 5);  // row chunk 0..511
    const int wv  = threadIdx.x >> 6;
    const int l   = threadIdx.x & 63;
    const int g   = l >> 4, q = l & 15;
    const int row0 = rc * 128 + wv * 32;

    const _Float16* frag = g_frag[p];
    const float*    bias = g_bias[p];
    const float*    fin  = g_fin[p];
    const f32x4 finB = *(const f32x4*)(fin + 4*g);
    const f32x4 finA = *(const f32x4*)(fin + 16 + 4*g);
    const float b56 = fin[32], ba5v = fin[33];
    const f32x4* a1w = (const f32x4*)(g_a1w[p] + l*16);
    const f32x4* a1b = (const f32x4*)(g_a1b[p] + l*16);

    // ---- operands for both row-tiles ---------------------------------------
    f16x8 bX[2];
    float xa[2];
#pragma unroll
    for (int t = 0; t < 2; ++t) {
        const float* xr = x + (size_t)(row0 + 16*t + q) * NP;
#pragma unroll
        for (int e = 0; e < 8; ++e) {
            const int k = 8*g + e;
            bX[t][e] = (_Float16)((k < 31) ? xr[k + (k >= p)] : 1.0f);
        }
        xa[t] = xr[p];
    }

    // ---- B1: 31->64 relu (bias folded in k=31 column) ----------------------
    f16x4 h[2][4];
#pragma unroll
    for (int Mt = 0; Mt < 4; ++Mt) {
        LOADW(Mt);
#pragma unroll
        for (int t = 0; t < 2; ++t) {
            f32x4 a{0.f, 0.f, 0.f, 0.f};
            MFMA2(bX[t], a);
            h[t][Mt] = relu_pack(a);
        }
    }
    f16x8 bk[2][2];
#pragma unroll
    for (int t = 0; t < 2; ++t) {
        bk[t][0] = cat8(h[t][0], h[t][1]);
        bk[t][1] = cat8(h[t][2], h[t][3]);
    }

    // ---- B2: 64->32 tanh (steps 4-7, bias 0-1) -----------------------------
    f16x4 u[2][2];
#pragma unroll
    for (int Mt = 0; Mt < 2; ++Mt) {
        const f32x4 binit = BIAS4(0 + Mt);
        f32x4 a[2] = {binit, binit};
#pragma unroll
        for (int ks = 0; ks < 2; ++ks) {
            LOADW(4 + 2*Mt + ks);
#pragma unroll
            for (int t = 0; t < 2; ++t) { MFMA2(bk[t][ks], a[t]); }
        }
#pragma unroll
        for (int t = 0; t < 2; ++t) u[t][Mt] = tanh_pack(a[t]);
    }
    f16x8 b2[2] = {cat8(u[0][0], u[0][1]), cat8(u[1][0], u[1][1])};

    // ---- B3: 32->32 tanh (steps 8-9, bias 2-3) -----------------------------
#pragma unroll
    for (int Mt = 0; Mt < 2; ++Mt) {
        const f32x4 binit = BIAS4(2 + Mt);
        LOADW(8 + Mt);
#pragma unroll
        for (int t = 0; t < 2; ++t) {
            f32x4 a = binit;
            MFMA2(b2[t], a);
            u[t][Mt] = tanh_pack(a);
        }
    }
    f16x8 b3[2] = {cat8(u[0][0], u[0][1]), cat8(u[1][0], u[1][1])};

    // ---- B4: 32->16 tanh (step 10, bias 4) + folded B5·B6 dot --------------
    float bv[2];
    {
        const f32x4 binit = BIAS4(4);
        LOADW(10);
#pragma unroll
        for (int t = 0; t < 2; ++t) {
            f32x4 a = binit;
            MFMA2(b3[t], a);
            const f32x4 c = tanh4(a);
            float s = finB[0] * c[0];
            s = fmaf(finB[1], c[1], s);
            s = fmaf(finB[2], c[2], s);
            s = fmaf(finB[3], c[3], s);
            s += __shfl_xor(s, 16);
            s += __shfl_xor(s, 32);
            bv[t] = s + b56;
        }
    }

    // ---- A1: 1->64 relu on VALU (weights pre-permuted to B-slot order) -----
    f16x8 bA[2][2];
#pragma unroll
    for (int ks = 0; ks < 2; ++ks) {
        const f32x4 w0 = a1w[2*ks],     v0 = a1b[2*ks];
        const f32x4 w1 = a1w[2*ks + 1], v1 = a1b[2*ks + 1];
#pragma unroll
        for (int t = 0; t < 2; ++t) {
            float c0[4], c1[4];
#pragma unroll
            for (int j = 0; j < 4; ++j) {
                c0[j] = fmaxf(fmaf(w0[j], xa[t], v0[j]), 0.f);
                c1[j] = fmaxf(fmaf(w1[j], xa[t], v1[j]), 0.f);
            }
            bA[t][ks] = cat8(pack4(c0[0], c0[1], c0[2], c0[3]),
                             pack4(c1[0], c1[1], c1[2], c1[3]));
        }
    }

    // ---- A2: 64->32 tanh (steps 11-14, bias 5-6) ---------------------------
#pragma unroll
    for (int Mt = 0; Mt < 2; ++Mt) {
        const f32x4 binit = BIAS4(5 + Mt);
        f32x4 a[2] = {binit, binit};
#pragma unroll
        for (int ks = 0; ks < 2; ++ks) {
            LOADW(11 + 2*Mt + ks);
#pragma unroll
            for (int t = 0; t < 2; ++t) { MFMA2(bA[t][ks], a[t]); }
        }
#pragma unroll
        for (int t = 0; t < 2; ++t) u[t][Mt] = tanh_pack(a[t]);
    }
    f16x8 a2[2] = {cat8(u[0][0], u[0][1]), cat8(u[1][0], u[1][1])};

    // ---- A3: 32->16 tanh (step 15, bias 7), halves swapped via xor32 -------
    f16x8 a3f[2];
    {
        const f32x4 binit = BIAS4(7);
        LOADW(15);
#pragma unroll
        for (int t = 0; t < 2; ++t) {
            f32x4 a = binit;
            MFMA2(a2[t], a);
            const f16x4 own = tanh_pack(a);
            const float2 ow = __builtin_bit_cast(float2, own);
            float2 pw;
            pw.x = __shfl_xor(ow.x, 32);
            pw.y = __shfl_xor(ow.y, 32);
            a3f[t] = cat8(own, __builtin_bit_cast(f16x4, pw));
        }
    }

    // ---- A4: 16->8 tanh (step 16, bias 8) + A5 dot + store ------------------
    {
        const f32x4 binit = BIAS4(8);
        LOADW(16);
#pragma unroll
        for (int t = 0; t < 2; ++t) {
            f32x4 a = binit;
            MFMA2(a3f[t], a);
            const f32x4 c = tanh4(a);
            float s = finA[0] * c[0];
            s = fmaf(finA[1], c[1], s);
            s = fmaf(finA[2], c[2], s);
            s = fmaf(finA[3], c[3], s);
            s += __shfl_xor(s, 16);
            s += __shfl_xor(s, 32);
            const float av = s + ba5v;
            if (g == 0) {
                const int grow = row0 + 16*t + q;
                reinterpret_cast<float2*>(out)[(size_t)grow * NP + p] =
                    make_float2(av, bv[t]);
            }
        }
    }
}

extern "C" void kernel_launch(void* const* d_in, const int* in_sizes, int n_in,
                              void* d_out, int out_size, void* d_ws,
                              size_t ws_size, hipStream_t stream) {
    const float* x   = (const float*)d_in[0];
    const float* Wa1 = (const float*)d_in[1];
    const float* ba1 = (const float*)d_in[2];
    const float* Wa2 = (const float*)d_in[3];
    const float* ba2 = (const float*)d_in[4];
    const float* Wa3 = (const float*)d_in[5];
    const float* ba3 = (const float*)d_in[6];
    const float* Wa4 = (const float*)d_in[7];
    const float* ba4 = (const float*)d_in[8];
    const float* Wa5 = (const float*)d_in[9];
    const float* ba5 = (const float*)d_in[10];
    const float* Wb1 = (const float*)d_in[11];
    const float* bb1 = (const float*)d_in[12];
    const float* Wb2 = (const float*)d_in[13];
    const float* bb2 = (const float*)d_in[14];
    const float* Wb3 = (const float*)d_in[15];
    const float* bb3 = (const float*)d_in[16];
    const float* Wb4 = (const float*)d_in[17];
    const float* bb4 = (const float*)d_in[18];
    const float* Wb5 = (const float*)d_in[19];
    const float* bb5 = (const float*)d_in[20];
    const float* Wb6 = (const float*)d_in[21];
    const float* bb6 = (const float*)d_in[22];

    prep_frags<<<dim3(NP), dim3(64), 0, stream>>>(
        Wa1, ba1, Wa2, ba2, Wa3, ba3, Wa4, ba4, Wa5, ba5,
        Wb1, bb1, Wb2, bb2, Wb3, bb3, Wb4, bb4, Wb5, bb5, Wb6, bb6);

    mlp_mfma<<<dim3(NROWS / 128 * NP), 256, 0, stream>>>(x, (float*)d_out);
}

// Round 12
// 283.035 us; speedup vs baseline: 3.3455x; 1.0026x over previous
//
#include <hip/hip_runtime.h>

#define NP 32
#define NROWS 65536

typedef _Float16 f16x8 __attribute__((ext_vector_type(8)));
typedef _Float16 f16x4 __attribute__((ext_vector_type(4)));
typedef _Float16 f16x2 __attribute__((ext_vector_type(2)));
typedef float    f32x4 __attribute__((ext_vector_type(4)));

#define FAST_RCP(x) __builtin_amdgcn_rcpf(x)

// tanh(x) = 1 - 2/(e^{2x}+1); saturates correctly at +-inf, no clamp needed.
__device__ __forceinline__ float fast_tanh(float v) {
    float e = __expf(2.0f * v);
    return fmaf(-2.0f, FAST_RCP(e + 1.0f), 1.0f);
}

__device__ __forceinline__ f16x4 pack4(float c0, float c1, float c2, float c3) {
    const f16x2 p01 = __builtin_bit_cast(f16x2, __builtin_amdgcn_cvt_pkrtz(c0, c1));
    const f16x2 p23 = __builtin_bit_cast(f16x2, __builtin_amdgcn_cvt_pkrtz(c2, c3));
    return __builtin_shufflevector(p01, p23, 0, 1, 2, 3);
}
__device__ __forceinline__ f16x8 cat8(f16x4 a, f16x4 b) {
    return __builtin_shufflevector(a, b, 0, 1, 2, 3, 4, 5, 6, 7);
}
__device__ __forceinline__ f16x4 tanh_pack(f32x4 a) {
    return pack4(fast_tanh(a[0]), fast_tanh(a[1]), fast_tanh(a[2]), fast_tanh(a[3]));
}
__device__ __forceinline__ f16x4 relu_pack(f32x4 a) {
    return pack4(fmaxf(a[0], 0.f), fmaxf(a[1], 0.f), fmaxf(a[2], 0.f), fmaxf(a[3], 0.f));
}
__device__ __forceinline__ f32x4 tanh4(f32x4 a) {
    return f32x4{fast_tanh(a[0]), fast_tanh(a[1]), fast_tanh(a[2]), fast_tanh(a[3])};
}

// ---- virtual-channel maps (verified r9-r11: absmax 0.0039) -----------------
__device__ __forceinline__ int col64(int k) {
    return 32 * (k >> 5) + 16 * ((k >> 2) & 1) + (((k >> 3) & 3) << 2) + (k & 3);
}
__device__ __forceinline__ int col32(int k) {
    return 16 * ((k >> 2) & 1) + ((k >> 3) << 2) + (k & 3);
}
__device__ __forceinline__ int col16(int k) {
    return (k & 3) | ((k >> 1) & 4) | ((k & 4) << 1);
}

// ---------------- prepacked weight storage (device globals) ----------------
// 17 MFMA steps: B1:s0-3 (bias in k=31 col) B2:s4-7 B3:s8-9 B4:s10
//                A2:s11-14 A3:s15 A4:s16 (order: Mt, ks)
// A-frag: row=lane&15 (=out), k=8*(l>>4)+e; columns pre-permuted per col maps.
// bias steps (C-layout out=16bMt+4g+j): B2:0-1 B3:2-3 B4:4 A2:5-6 A3:7 A4:8
__device__ __align__(16) _Float16 g_frag[NP][17 * 2 * 64 * 8]; // hi/lo pairs
__device__ __align__(16) float    g_bias[NP][9 * 64 * 4];
__device__ __align__(16) float    g_a1w [NP][64 * 16];  // A1 in B-slot order
__device__ __align__(16) float    g_a1b [NP][64 * 16];
// fin: [0..15]=W56 (Wb6·Wb5), [16..31]=Wa5 zero-padded, [32]=b56, [33]=ba5
__device__ __align__(16) float    g_fin [NP][36];

__global__ void prep_frags(
    const float* __restrict__ Wa1, const float* __restrict__ ba1,
    const float* __restrict__ Wa2, const float* __restrict__ ba2,
    const float* __restrict__ Wa3, const float* __restrict__ ba3,
    const float* __restrict__ Wa4, const float* __restrict__ ba4,
    const float* __restrict__ Wa5, const float* __restrict__ ba5,
    const float* __restrict__ Wb1, const float* __restrict__ bb1,
    const float* __restrict__ Wb2, const float* __restrict__ bb2,
    const float* __restrict__ Wb3, const float* __restrict__ bb3,
    const float* __restrict__ Wb4, const float* __restrict__ bb4,
    const float* __restrict__ Wb5, const float* __restrict__ bb5,
    const float* __restrict__ Wb6, const float* __restrict__ bb6) {
    const int p = blockIdx.x;
    const int l = threadIdx.x;          // 0..63
    const int g = l >> 4, q = l & 15;

    const int sw[17]  = {0,0,0,0, 1,1,1,1, 2,2, 3, 4,4,4,4, 5, 6};
    const int sMt[17] = {0,1,2,3, 0,0,1,1, 0,1, 0, 0,0,1,1, 0, 0};
    const int sks[17] = {0,0,0,0, 0,1,0,1, 0,0, 0, 0,1,0,1, 0, 0};
    const int OO[7] = {64,32,32,16,32,16, 8};
    const int II[7] = {31,64,32,32,64,32,16};
    const float* WS[7] = {Wb1 + p*1984, Wb2 + p*2048, Wb3 + p*1024,
                          Wb4 + p*512,  Wa2 + p*2048, Wa3 + p*512,
                          Wa4 + p*128};
    const float* b1s = bb1 + p*64;
    for (int s = 0; s < 17; ++s) {
        const int w = sw[s], O = OO[w], I = II[w];
        const float* W = WS[w];
        for (int e = 0; e < 8; ++e) {
            const int kk = 32*sks[s] + 8*g + e;   // layer-k slot
            const int o  = 16*sMt[s] + q;         // out (= A row)
            float wv = 0.0f;
            if (o < O) {
                if (s < 4) {        // B1: direct x order; col 31 = bias
                    wv = (kk < 31) ? W[o*31 + kk] : (kk == 31 ? b1s[o] : 0.0f);
                } else if (w == 1 || w == 4) {          // 64-wide input
                    wv = W[o*I + col64(kk)];
                } else if (w == 6) {                    // A4: 16-wide input
                    wv = (kk < 16) ? W[o*I + col16(kk)] : 0.0f;
                } else {                                // 32-wide input
                    wv = W[o*I + col32(kk)];
                }
            }
            const _Float16 hi = (_Float16)wv;
            const _Float16 lo = (_Float16)(wv - (float)hi);
            g_frag[p][((s*2 + 0)*64 + l)*8 + e] = hi;
            g_frag[p][((s*2 + 1)*64 + l)*8 + e] = lo;
        }
    }
    const int bw[9]  = {0,0, 1,1, 2, 3,3, 4, 5};
    const int bMt[9] = {0,1, 0,1, 0, 0,1, 0, 0};
    const float* BS[6] = {bb2 + p*32, bb3 + p*32, bb4 + p*16,
                          ba2 + p*32, ba3 + p*16, ba4 + p*8};
    const int BO[6] = {32,32,16,32,16,8};
    for (int bs = 0; bs < 9; ++bs) {
        const int w = bw[bs];
        for (int j = 0; j < 4; ++j) {
            const int o = 16*bMt[bs] + 4*g + j;
            g_bias[p][(bs*64 + l)*4 + j] = (o < BO[w]) ? BS[w][o] : 0.0f;
        }
    }
    // A1 weights directly in B-slot order (out channel = col64 of slot)
    for (int idx = 0; idx < 16; ++idx) {
        const int ks = idx >> 3, e = idx & 7;
        const int c = col64(32*ks + 8*g + e);
        g_a1w[p][l*16 + idx] = Wa1[p*64 + c];
        g_a1b[p][l*16 + idx] = ba1[p*64 + c];
    }
    if (l == 0) {
        // fold B5 (16->8) and B6 (8->1): W56 = Wb6·Wb5, b56 = Wb6·bb5 + bb6
        for (int i = 0; i < 16; ++i) {
            float s = 0.0f;
            for (int o = 0; o < 8; ++o)
                s += Wb6[p*8 + o] * Wb5[p*128 + o*16 + i];
            g_fin[p][i] = s;
        }
        for (int i = 0; i < 16; ++i)
            g_fin[p][16 + i] = (i < 8) ? Wa5[p*8 + i] : 0.0f;
        float s = bb6[p];
        for (int o = 0; o < 8; ++o) s += Wb6[p*8 + o] * bb5[p*8 + o];
        g_fin[p][32] = s;
        g_fin[p][33] = ba5[p];
    }
}

// ---------------- main kernel: zero LDS, step-major, SW-PIPELINED ----------
// r11 lesson: at VGPR=44 the scheduler never hoists the ~40 step loads, so
// each step serializes a full VMEM latency (~5% issue duty/wave). Here every
// weight load is explicitly issued ONE STEP EARLY into a rotating (nlo,nhi)
// pair, and each group's bias ONE GROUP EARLY (nb) — bounded depth, so the
// r10 LICM spill cannot recur (peak live ~95 VGPR).
#define LOADN(s) \
    nlo = *(const f16x8*)(frag + (((s)*2 + 1)*64 + l)*8); \
    nhi = *(const f16x8*)(frag + (((s)*2 + 0)*64 + l)*8);
#define ROT() clo = nlo; chi = nhi;
#define MFMA2C(bop, acc) \
    acc = __builtin_amdgcn_mfma_f32_16x16x32_f16(clo, bop, acc, 0, 0, 0); \
    acc = __builtin_amdgcn_mfma_f32_16x16x32_f16(chi, bop, acc, 0, 0, 0);
#define BIAS4(bs) (*(const f32x4*)(bias + ((bs)*64 + l)*4))

__global__ __launch_bounds__(256, 4) void mlp_mfma(
    const float* __restrict__ x, float* __restrict__ out) {
    // Block remap: 32 p-blocks of one row chunk consecutive on one XCD so
    // partial 8B output writes merge in L2 (verified r7: 162 -> 16.4 MB).
    const int L   = blockIdx.x;          // 0..16383
    const int xcd = L & 7;
    const int m   = L >> 3;
    const int p   = m & 31;              // feature
    const int rc  = xcd + 8 * (m >> 5);  // row chunk 0..511
    const int wv  = threadIdx.x >> 6;
    const int l   = threadIdx.x & 63;
    const int g   = l >> 4, q = l & 15;
    const int row0 = rc * 128 + wv * 32;

    const _Float16* frag = g_frag[p];
    const float*    bias = g_bias[p];
    const float*    fin  = g_fin[p];

    // ---- x operands first (deepest latency) --------------------------------
    f16x8 bX[2];
    float xa[2];
#pragma unroll
    for (int t = 0; t < 2; ++t) {
        const float* xr = x + (size_t)(row0 + 16*t + q) * NP;
#pragma unroll
        for (int e = 0; e < 8; ++e) {
            const int k = 8*g + e;
            bX[t][e] = (_Float16)((k < 31) ? xr[k + (k >= p)] : 1.0f);
        }
        xa[t] = xr[p];
    }

    // ---- pipeline registers -------------------------------------------------
    f16x8 clo, chi, nlo, nhi;
    f32x4 cb, nb;
    LOADN(0);
    nb = BIAS4(0);

    // ---- B1: 31->64 relu (bias folded in k=31 column), steps 0-3 -----------
    f16x4 h[2][4];
#pragma unroll
    for (int Mt = 0; Mt < 4; ++Mt) {
        ROT();
        LOADN(Mt + 1);                    // prefetch next step (1..4)
        f32x4 a0{0.f,0.f,0.f,0.f}, a1{0.f,0.f,0.f,0.f};
        MFMA2C(bX[0], a0);
        MFMA2C(bX[1], a1);
        h[0][Mt] = relu_pack(a0);
        h[1][Mt] = relu_pack(a1);
    }
    f16x8 bk[2][2];
#pragma unroll
    for (int t = 0; t < 2; ++t) {
        bk[t][0] = cat8(h[t][0], h[t][1]);
        bk[t][1] = cat8(h[t][2], h[t][3]);
    }

    // ---- B2: 64->32 tanh (steps 4-7, bias 0-1) -----------------------------
    f16x4 u[2][2];
#pragma unroll
    for (int Mt = 0; Mt < 2; ++Mt) {
        cb = nb; nb = BIAS4(1 + Mt);      // prefetch next group's bias (1,2)
        f32x4 a0 = cb, a1 = cb;
        ROT();
        LOADN(5 + 2*Mt);
        MFMA2C(bk[0][0], a0);
        MFMA2C(bk[1][0], a1);
        ROT();
        LOADN(6 + 2*Mt);                  // 6,7 then 8 (B3's first)
        MFMA2C(bk[0][1], a0);
        MFMA2C(bk[1][1], a1);
        u[0][Mt] = tanh_pack(a0);
        u[1][Mt] = tanh_pack(a1);
    }
    f16x8 b2[2] = {cat8(u[0][0], u[0][1]), cat8(u[1][0], u[1][1])};

    // ---- mid-chain table prefetch: A1 weights + final dots ------------------
    const f32x4* a1wp = (const f32x4*)(g_a1w[p] + l*16);
    const f32x4* a1bp = (const f32x4*)(g_a1b[p] + l*16);
    f32x4 a1w[4], a1b[4];
#pragma unroll
    for (int i = 0; i < 4; ++i) { a1w[i] = a1wp[i]; a1b[i] = a1bp[i]; }
    const f32x4 finB = *(const f32x4*)(fin + 4*g);
    const f32x4 finA = *(const f32x4*)(fin + 16 + 4*g);
    const float b56 = fin[32], ba5v = fin[33];

    // ---- B3: 32->32 tanh (steps 8-9, bias 2-3) -----------------------------
#pragma unroll
    for (int Mt = 0; Mt < 2; ++Mt) {
        cb = nb; nb = BIAS4(3 + Mt);      // prefetch bias 3,4
        ROT();
        LOADN(9 + Mt);                    // 9 then 10 (B4)
        f32x4 a0 = cb, a1 = cb;
        MFMA2C(b2[0], a0);
        MFMA2C(b2[1], a1);
        u[0][Mt] = tanh_pack(a0);
        u[1][Mt] = tanh_pack(a1);
    }
    f16x8 b3[2] = {cat8(u[0][0], u[0][1]), cat8(u[1][0], u[1][1])};

    // ---- B4: 32->16 tanh (step 10, bias 4) + folded B5·B6 dot --------------
    float bv[2];
    {
        cb = nb; nb = BIAS4(5);           // prefetch bias 5 (A2 Mt0)
        ROT();
        LOADN(11);                        // prefetch A2's first step
        f32x4 a0 = cb, a1 = cb;
        MFMA2C(b3[0], a0);
        MFMA2C(b3[1], a1);
#pragma unroll
        for (int t = 0; t < 2; ++t) {
            const f32x4 c = tanh4(t ? a1 : a0);
            float s = finB[0] * c[0];
            s = fmaf(finB[1], c[1], s);
            s = fmaf(finB[2], c[2], s);
            s = fmaf(finB[3], c[3], s);
            s += __shfl_xor(s, 16);
            s += __shfl_xor(s, 32);
            bv[t] = s + b56;
        }
    }

    // ---- A1: 1->64 relu on VALU (weights pre-permuted to B-slot order) -----
    f16x8 bA[2][2];
#pragma unroll
    for (int ks = 0; ks < 2; ++ks) {
#pragma unroll
        for (int t = 0; t < 2; ++t) {
            float c0[4], c1[4];
#pragma unroll
            for (int j = 0; j < 4; ++j) {
                c0[j] = fmaxf(fmaf(a1w[2*ks][j],   xa[t], a1b[2*ks][j]),   0.f);
                c1[j] = fmaxf(fmaf(a1w[2*ks+1][j], xa[t], a1b[2*ks+1][j]), 0.f);
            }
            bA[t][ks] = cat8(pack4(c0[0], c0[1], c0[2], c0[3]),
                             pack4(c1[0], c1[1], c1[2], c1[3]));
        }
    }

    // ---- A2: 64->32 tanh (steps 11-14, bias 5-6) ---------------------------
#pragma unroll
    for (int Mt = 0; Mt < 2; ++Mt) {
        cb = nb; nb = BIAS4(6 + Mt);      // prefetch bias 6,7
        f32x4 a0 = cb, a1 = cb;
        ROT();
        LOADN(12 + 2*Mt);
        MFMA2C(bA[0][0], a0);
        MFMA2C(bA[1][0], a1);
        ROT();
        LOADN(13 + 2*Mt);                 // 13,14 then 15 (A3)
        MFMA2C(bA[0][1], a0);
        MFMA2C(bA[1][1], a1);
        u[0][Mt] = tanh_pack(a0);
        u[1][Mt] = tanh_pack(a1);
    }
    f16x8 a2[2] = {cat8(u[0][0], u[0][1]), cat8(u[1][0], u[1][1])};

    // ---- A3: 32->16 tanh (step 15, bias 7), halves swapped via xor32 -------
    f16x8 a3f[2];
    {
        cb = nb; nb = BIAS4(8);           // prefetch bias 8 (A4)
        ROT();
        LOADN(16);                        // prefetch A4 weights
        f32x4 a0 = cb, a1 = cb;
        MFMA2C(a2[0], a0);
        MFMA2C(a2[1], a1);
#pragma unroll
        for (int t = 0; t < 2; ++t) {
            const f16x4 own = tanh_pack(t ? a1 : a0);
            const float2 ow = __builtin_bit_cast(float2, own);
            float2 pw;
            pw.x = __shfl_xor(ow.x, 32);
            pw.y = __shfl_xor(ow.y, 32);
            a3f[t] = cat8(own, __builtin_bit_cast(f16x4, pw));
        }
    }

    // ---- A4: 16->8 tanh (step 16, bias 8) + A5 dot + store ------------------
    {
        cb = nb;
        ROT();                            // last step: nothing left to prefetch
        f32x4 a0 = cb, a1 = cb;
        MFMA2C(a3f[0], a0);
        MFMA2C(a3f[1], a1);
#pragma unroll
        for (int t = 0; t < 2; ++t) {
            const f32x4 c = tanh4(t ? a1 : a0);
            float s = finA[0] * c[0];
            s = fmaf(finA[1], c[1], s);
            s = fmaf(finA[2], c[2], s);
            s = fmaf(finA[3], c[3], s);
            s += __shfl_xor(s, 16);
            s += __shfl_xor(s, 32);
            const float av = s + ba5v;
            if (g == 0) {
                const int grow = row0 + 16*t + q;
                reinterpret_cast<float2*>(out)[(size_t)grow * NP + p] =
                    make_float2(av, bv[t]);
            }
        }
    }
}

extern "C" void kernel_launch(void* const* d_in, const int* in_sizes, int n_in,
                              void* d_out, int out_size, void* d_ws,
                              size_t ws_size, hipStream_t stream) {
    const float* x   = (const float*)d_in[0];
    const float* Wa1 = (const float*)d_in[1];
    const float* ba1 = (const float*)d_in[2];
    const float* Wa2 = (const float*)d_in[3];
    const float* ba2 = (const float*)d_in[4];
    const float* Wa3 = (const float*)d_in[5];
    const float* ba3 = (const float*)d_in[6];
    const float* Wa4 = (const float*)d_in[7];
    const float* ba4 = (const float*)d_in[8];
    const float* Wa5 = (const float*)d_in[9];
    const float* ba5 = (const float*)d_in[10];
    const float* Wb1 = (const float*)d_in[11];
    const float* bb1 = (const float*)d_in[12];
    const float* Wb2 = (const float*)d_in[13];
    const float* bb2 = (const float*)d_in[14];
    const float* Wb3 = (const float*)d_in[15];
    const float* bb3 = (const float*)d_in[16];
    const float* Wb4 = (const float*)d_in[17];
    const float* bb4 = (const float*)d_in[18];
    const float* Wb5 = (const float*)d_in[19];
    const float* bb5 = (const float*)d_in[20];
    const float* Wb6 = (const float*)d_in[21];
    const float* bb6 = (const float*)d_in[22];

    prep_frags<<<dim3(NP), dim3(64), 0, stream>>>(
        Wa1, ba1, Wa2, ba2, Wa3, ba3, Wa4, ba4, Wa5, ba5,
        Wb1, bb1, Wb2, bb2, Wb3, bb3, Wb4, bb4, Wb5, bb5, Wb6, bb6);

    mlp_mfma<<<dim3(NROWS / 128 * NP), 256, 0, stream>>>(x, (float*)d_out);
}

// Round 13
// 241.432 us; speedup vs baseline: 3.9219x; 1.1723x over previous
//
#include <hip/hip_runtime.h>

#define NP 32
#define NROWS 65536

typedef _Float16 f16x8 __attribute__((ext_vector_type(8)));
typedef _Float16 f16x4 __attribute__((ext_vector_type(4)));
typedef _Float16 f16x2 __attribute__((ext_vector_type(2)));
typedef float    f32x4 __attribute__((ext_vector_type(4)));

#define FAST_RCP(x) __builtin_amdgcn_rcpf(x)

// tanh(x) = 1 - 2/(e^{2x}+1); saturates correctly at +-inf, no clamp needed.
__device__ __forceinline__ float fast_tanh(float v) {
    float e = __expf(2.0f * v);
    return fmaf(-2.0f, FAST_RCP(e + 1.0f), 1.0f);
}

__device__ __forceinline__ f16x4 pack4(float c0, float c1, float c2, float c3) {
    const f16x2 p01 = __builtin_bit_cast(f16x2, __builtin_amdgcn_cvt_pkrtz(c0, c1));
    const f16x2 p23 = __builtin_bit_cast(f16x2, __builtin_amdgcn_cvt_pkrtz(c2, c3));
    return __builtin_shufflevector(p01, p23, 0, 1, 2, 3);
}
__device__ __forceinline__ f16x8 cat8(f16x4 a, f16x4 b) {
    return __builtin_shufflevector(a, b, 0, 1, 2, 3, 4, 5, 6, 7);
}
__device__ __forceinline__ f16x4 tanh_pack(f32x4 a) {
    return pack4(fast_tanh(a[0]), fast_tanh(a[1]), fast_tanh(a[2]), fast_tanh(a[3]));
}
__device__ __forceinline__ f16x4 relu_pack(f32x4 a) {
    return pack4(fmaxf(a[0], 0.f), fmaxf(a[1], 0.f), fmaxf(a[2], 0.f), fmaxf(a[3], 0.f));
}
__device__ __forceinline__ f32x4 tanh4(f32x4 a) {
    return f32x4{fast_tanh(a[0]), fast_tanh(a[1]), fast_tanh(a[2]), fast_tanh(a[3])};
}

// ---- virtual-channel maps (verified r9-r12: absmax 0.0039) -----------------
__device__ __forceinline__ int col64(int k) {
    return 32 * (k >> 5) + 16 * ((k >> 2) & 1) + (((k >> 3) & 3) << 2) + (k & 3);
}
__device__ __forceinline__ int col32(int k) {
    return 16 * ((k >> 2) & 1) + ((k >> 3) << 2) + (k & 3);
}
__device__ __forceinline__ int col16(int k) {
    return (k & 3) | ((k >> 1) & 4) | ((k & 4) << 1);
}

// ---------------- prepacked weight storage (device globals) ----------------
// 17 MFMA steps: B1:s0-3 (bias in k=31 col) B2:s4-7 B3:s8-9 B4:s10
//                A2:s11-14 A3:s15 A4:s16 (order: Mt, ks)
// A-frag: row=lane&15 (=out), k=8*(l>>4)+e; columns pre-permuted per col maps.
// bias steps (C-layout out=16bMt+4g+j): B2:0-1 B3:2-3 B4:4 A2:5-6 A3:7 A4:8
__device__ __align__(16) _Float16 g_frag[NP][17 * 2 * 64 * 8]; // hi/lo pairs
__device__ __align__(16) float    g_bias[NP][9 * 64 * 4];
__device__ __align__(16) float    g_a1w [NP][64 * 16];  // A1 in B-slot order
__device__ __align__(16) float    g_a1b [NP][64 * 16];
// fin: [0..15]=W56 (Wb6·Wb5), [16..31]=Wa5 zero-padded, [32]=b56, [33]=ba5
__device__ __align__(16) float    g_fin [NP][36];

__global__ void prep_frags(
    const float* __restrict__ Wa1, const float* __restrict__ ba1,
    const float* __restrict__ Wa2, const float* __restrict__ ba2,
    const float* __restrict__ Wa3, const float* __restrict__ ba3,
    const float* __restrict__ Wa4, const float* __restrict__ ba4,
    const float* __restrict__ Wa5, const float* __restrict__ ba5,
    const float* __restrict__ Wb1, const float* __restrict__ bb1,
    const float* __restrict__ Wb2, const float* __restrict__ bb2,
    const float* __restrict__ Wb3, const float* __restrict__ bb3,
    const float* __restrict__ Wb4, const float* __restrict__ bb4,
    const float* __restrict__ Wb5, const float* __restrict__ bb5,
    const float* __restrict__ Wb6, const float* __restrict__ bb6) {
    const int p = blockIdx.x;
    const int l = threadIdx.x;          // 0..63
    const int g = l >> 4, q = l & 15;

    const int sw[17]  = {0,0,0,0, 1,1,1,1, 2,2, 3, 4,4,4,4, 5, 6};
    const int sMt[17] = {0,1,2,3, 0,0,1,1, 0,1, 0, 0,0,1,1, 0, 0};
    const int sks[17] = {0,0,0,0, 0,1,0,1, 0,0, 0, 0,1,0,1, 0, 0};
    const int OO[7] = {64,32,32,16,32,16, 8};
    const int II[7] = {31,64,32,32,64,32,16};
    const float* WS[7] = {Wb1 + p*1984, Wb2 + p*2048, Wb3 + p*1024,
                          Wb4 + p*512,  Wa2 + p*2048, Wa3 + p*512,
                          Wa4 + p*128};
    const float* b1s = bb1 + p*64;
    for (int s = 0; s < 17; ++s) {
        const int w = sw[s], O = OO[w], I = II[w];
        const float* W = WS[w];
        for (int e = 0; e < 8; ++e) {
            const int kk = 32*sks[s] + 8*g + e;   // layer-k slot
            const int o  = 16*sMt[s] + q;         // out (= A row)
            float wv = 0.0f;
            if (o < O) {
                if (s < 4) {        // B1: direct x order; col 31 = bias
                    wv = (kk < 31) ? W[o*31 + kk] : (kk == 31 ? b1s[o] : 0.0f);
                } else if (w == 1 || w == 4) {          // 64-wide input
                    wv = W[o*I + col64(kk)];
                } else if (w == 6) {                    // A4: 16-wide input
                    wv = (kk < 16) ? W[o*I + col16(kk)] : 0.0f;
                } else {                                // 32-wide input
                    wv = W[o*I + col32(kk)];
                }
            }
            const _Float16 hi = (_Float16)wv;
            const _Float16 lo = (_Float16)(wv - (float)hi);
            g_frag[p][((s*2 + 0)*64 + l)*8 + e] = hi;
            g_frag[p][((s*2 + 1)*64 + l)*8 + e] = lo;
        }
    }
    const int bw[9]  = {0,0, 1,1, 2, 3,3, 4, 5};
    const int bMt[9] = {0,1, 0,1, 0, 0,1, 0, 0};
    const float* BS[6] = {bb2 + p*32, bb3 + p*32, bb4 + p*16,
                          ba2 + p*32, ba3 + p*16, ba4 + p*8};
    const int BO[6] = {32,32,16,32,16,8};
    for (int bs = 0; bs < 9; ++bs) {
        const int w = bw[bs];
        for (int j = 0; j < 4; ++j) {
            const int o = 16*bMt[bs] + 4*g + j;
            g_bias[p][(bs*64 + l)*4 + j] = (o < BO[w]) ? BS[w][o] : 0.0f;
        }
    }
    // A1 weights directly in B-slot order (out channel = col64 of slot)
    for (int idx = 0; idx < 16; ++idx) {
        const int ks = idx >> 3, e = idx & 7;
        const int c = col64(32*ks + 8*g + e);
        g_a1w[p][l*16 + idx] = Wa1[p*64 + c];
        g_a1b[p][l*16 + idx] = ba1[p*64 + c];
    }
    if (l == 0) {
        // fold B5 (16->8) and B6 (8->1): W56 = Wb6·Wb5, b56 = Wb6·bb5 + bb6
        for (int i = 0; i < 16; ++i) {
            float s = 0.0f;
            for (int o = 0; o < 8; ++o)
                s += Wb6[p*8 + o] * Wb5[p*128 + o*16 + i];
            g_fin[p][i] = s;
        }
        for (int i = 0; i < 16; ++i)
            g_fin[p][16 + i] = (i < 8) ? Wa5[p*8 + i] : 0.0f;
        float s = bb6[p];
        for (int o = 0; o < 8; ++o) s += Wb6[p*8 + o] * bb5[p*8 + o];
        g_fin[p][32] = s;
        g_fin[p][33] = ba5[p];
    }
}

// ---------------- main kernel ------------------------------------------------
// r12 lesson: source-level prefetch of GLOBAL weight loads gets re-sunk by the
// scheduler, and each step then eats a serial ~200cyc L2-hit (35KB/p table
// thrashes L1; 2.3GB L2 traffic). Fix: (1) stage the whole frag table in LDS
// once per block — all 4 waves share the same p — so per-step fetch is a
// ~60cyc ds_read; (2) t=4 row-tiles/wave so per-step compute (~300cyc) covers
// it; (3) one-step-ahead ds_read double-buffer (bounded depth, no r10 spill).
#define LOADN(s) \
    nlo = *(const f16x8*)(wlds + (((s)*2 + 1)*64 + l)*8); \
    nhi = *(const f16x8*)(wlds + (((s)*2 + 0)*64 + l)*8);
#define ROT() clo = nlo; chi = nhi;
#define MFMA2C(bop, acc) \
    acc = __builtin_amdgcn_mfma_f32_16x16x32_f16(clo, bop, acc, 0, 0, 0); \
    acc = __builtin_amdgcn_mfma_f32_16x16x32_f16(chi, bop, acc, 0, 0, 0);
#define BIAS4(bs) (*(const f32x4*)(bias + ((bs)*64 + l)*4))

__global__ __launch_bounds__(256, 3) void mlp_mfma(
    const float* __restrict__ x, float* __restrict__ out) {
    __shared__ __align__(16) _Float16 wlds[17 * 2 * 64 * 8];  // 34816 B

    // Block remap: 32 p-blocks of one row chunk consecutive on one XCD so
    // partial 8B output writes merge in L2 (verified r7: 162 -> 16.4 MB).
    const int L   = blockIdx.x;          // 0..8191
    const int xcd = L & 7;
    const int m   = L >> 3;
    const int p   = m & 31;              // feature
    const int rc  = xcd + 8 * (m >> 5);  // row chunk 0..255
    const int wv  = threadIdx.x >> 6;
    const int l   = threadIdx.x & 63;
    const int g   = l >> 4, q = l & 15;
    const int row0 = rc * 256 + wv * 64;

    // ---- stage the frag table to LDS (once per block, shared by 4 waves) ---
    {
        const uint4* src = (const uint4*)(g_frag[p]);
        uint4* dst = (uint4*)wlds;
        for (int i = threadIdx.x; i < 34816 / 16; i += 256) dst[i] = src[i];
    }

    const float* bias = g_bias[p];
    const float* fin  = g_fin[p];

    // ---- x operands (overlap with staging, before the barrier) -------------
    f16x8 bX[4];
    float xa[4];
#pragma unroll
    for (int t = 0; t < 4; ++t) {
        const float* xr = x + (size_t)(row0 + 16*t + q) * NP;
#pragma unroll
        for (int e = 0; e < 8; ++e) {
            const int k = 8*g + e;
            bX[t][e] = (_Float16)((k < 31) ? xr[k + (k >= p)] : 1.0f);
        }
        xa[t] = xr[p];
    }
    const f32x4 finB = *(const f32x4*)(fin + 4*g);
    const f32x4 finA = *(const f32x4*)(fin + 16 + 4*g);
    const float b56 = fin[32], ba5v = fin[33];

    __syncthreads();

    // ---- pipeline registers --------------------------------------------------
    f16x8 clo, chi, nlo, nhi;
    f32x4 cb, nb;
    LOADN(0);
    nb = BIAS4(0);

    // ---- B1: 31->64 relu (bias folded in k=31 column), steps 0-3 -----------
    f16x4 h[4][4];
#pragma unroll
    for (int Mt = 0; Mt < 4; ++Mt) {
        ROT();
        LOADN(Mt + 1);                    // prefetch next step (1..4)
#pragma unroll
        for (int t = 0; t < 4; ++t) {
            f32x4 a{0.f, 0.f, 0.f, 0.f};
            MFMA2C(bX[t], a);
            h[t][Mt] = relu_pack(a);
        }
    }
    f16x8 bk[4][2];
#pragma unroll
    for (int t = 0; t < 4; ++t) {
        bk[t][0] = cat8(h[t][0], h[t][1]);
        bk[t][1] = cat8(h[t][2], h[t][3]);
    }

    // ---- B2: 64->32 tanh (steps 4-7, bias 0-1) -----------------------------
    f16x4 u[4][2];
#pragma unroll
    for (int Mt = 0; Mt < 2; ++Mt) {
        cb = nb; nb = BIAS4(1 + Mt);      // prefetch next group's bias (1,2)
        f32x4 a[4] = {cb, cb, cb, cb};
        ROT();
        LOADN(5 + 2*Mt);
#pragma unroll
        for (int t = 0; t < 4; ++t) { MFMA2C(bk[t][0], a[t]); }
        ROT();
        LOADN(6 + 2*Mt);                  // 6,7 then 8 (B3's first)
#pragma unroll
        for (int t = 0; t < 4; ++t) { MFMA2C(bk[t][1], a[t]); }
#pragma unroll
        for (int t = 0; t < 4; ++t) u[t][Mt] = tanh_pack(a[t]);
    }
    f16x8 b2[4];
#pragma unroll
    for (int t = 0; t < 4; ++t) b2[t] = cat8(u[t][0], u[t][1]);

    // ---- B3: 32->32 tanh (steps 8-9, bias 2-3) -----------------------------
#pragma unroll
    for (int Mt = 0; Mt < 2; ++Mt) {
        cb = nb; nb = BIAS4(3 + Mt);      // prefetch bias 3,4
        ROT();
        LOADN(9 + Mt);                    // 9 then 10 (B4)
#pragma unroll
        for (int t = 0; t < 4; ++t) {
            f32x4 a = cb;
            MFMA2C(b2[t], a);
            u[t][Mt] = tanh_pack(a);
        }
    }
    f16x8 b3[4];
#pragma unroll
    for (int t = 0; t < 4; ++t) b3[t] = cat8(u[t][0], u[t][1]);

    // ---- A1 tables: issue here so B4's compute covers their L2 latency -----
    const f32x4* a1wp = (const f32x4*)(g_a1w[p] + l*16);
    const f32x4* a1bp = (const f32x4*)(g_a1b[p] + l*16);
    f32x4 a1w[4], a1b[4];
#pragma unroll
    for (int i = 0; i < 4; ++i) { a1w[i] = a1wp[i]; a1b[i] = a1bp[i]; }

    // ---- B4: 32->16 tanh (step 10, bias 4) + folded B5·B6 dot --------------
    float bv[4];
    {
        cb = nb; nb = BIAS4(5);           // prefetch bias 5 (A2 Mt0)
        ROT();
        LOADN(11);                        // prefetch A2's first step
#pragma unroll
        for (int t = 0; t < 4; ++t) {
            f32x4 a = cb;
            MFMA2C(b3[t], a);
            const f32x4 c = tanh4(a);
            float s = finB[0] * c[0];
            s = fmaf(finB[1], c[1], s);
            s = fmaf(finB[2], c[2], s);
            s = fmaf(finB[3], c[3], s);
            s += __shfl_xor(s, 16);
            s += __shfl_xor(s, 32);
            bv[t] = s + b56;
        }
    }

    // ---- A1: 1->64 relu on VALU (weights pre-permuted to B-slot order) -----
    f16x8 bA[4][2];
#pragma unroll
    for (int ks = 0; ks < 2; ++ks) {
#pragma unroll
        for (int t = 0; t < 4; ++t) {
            float c0[4], c1[4];
#pragma unroll
            for (int j = 0; j < 4; ++j) {
                c0[j] = fmaxf(fmaf(a1w[2*ks][j],   xa[t], a1b[2*ks][j]),   0.f);
                c1[j] = fmaxf(fmaf(a1w[2*ks+1][j], xa[t], a1b[2*ks+1][j]), 0.f);
            }
            bA[t][ks] = cat8(pack4(c0[0], c0[1], c0[2], c0[3]),
                             pack4(c1[0], c1[1], c1[2], c1[3]));
        }
    }

    // ---- A2: 64->32 tanh (steps 11-14, bias 5-6) ---------------------------
#pragma unroll
    for (int Mt = 0; Mt < 2; ++Mt) {
        cb = nb; nb = BIAS4(6 + Mt);      // prefetch bias 6,7
        f32x4 a[4] = {cb, cb, cb, cb};
        ROT();
        LOADN(12 + 2*Mt);
#pragma unroll
        for (int t = 0; t < 4; ++t) { MFMA2C(bA[t][0], a[t]); }
        ROT();
        LOADN(13 + 2*Mt);                 // 13,14 then 15 (A3)
#pragma unroll
        for (int t = 0; t < 4; ++t) { MFMA2C(bA[t][1], a[t]); }
#pragma unroll
        for (int t = 0; t < 4; ++t) u[t][Mt] = tanh_pack(a[t]);
    }
    f16x8 a2[4];
#pragma unroll
    for (int t = 0; t < 4; ++t) a2[t] = cat8(u[t][0], u[t][1]);

    // ---- A3: 32->16 tanh (step 15, bias 7), halves swapped via xor32 -------
    f16x8 a3f[4];
    {
        cb = nb; nb = BIAS4(8);           // prefetch bias 8 (A4)
        ROT();
        LOADN(16);                        // prefetch A4 weights
#pragma unroll
        for (int t = 0; t < 4; ++t) {
            f32x4 a = cb;
            MFMA2C(a2[t], a);
            const f16x4 own = tanh_pack(a);
            const float2 ow = __builtin_bit_cast(float2, own);
            float2 pw;
            pw.x = __shfl_xor(ow.x, 32);
            pw.y = __shfl_xor(ow.y, 32);
            a3f[t] = cat8(own, __builtin_bit_cast(f16x4, pw));
        }
    }

    // ---- A4: 16->8 tanh (step 16, bias 8) + A5 dot + store ------------------
    {
        cb = nb;
        ROT();                            // last step: nothing left to prefetch
#pragma unroll
        for (int t = 0; t < 4; ++t) {
            f32x4 a = cb;
            MFMA2C(a3f[t], a);
            const f32x4 c = tanh4(a);
            float s = finA[0] * c[0];
            s = fmaf(finA[1], c[1], s);
            s = fmaf(finA[2], c[2], s);
            s = fmaf(finA[3], c[3], s);
            s += __shfl_xor(s, 16);
            s += __shfl_xor(s, 32);
            const float av = s + ba5v;
            if (g == 0) {
                const int grow = row0 + 16*t + q;
                reinterpret_cast<float2*>(out)[(size_t)grow * NP + p] =
                    make_float2(av, bv[t]);
            }
        }
    }
}

extern "C" void kernel_launch(void* const* d_in, const int* in_sizes, int n_in,
                              void* d_out, int out_size, void* d_ws,
                              size_t ws_size, hipStream_t stream) {
    const float* x   = (const float*)d_in[0];
    const float* Wa1 = (const float*)d_in[1];
    const float* ba1 = (const float*)d_in[2];
    const float* Wa2 = (const float*)d_in[3];
    const float* ba2 = (const float*)d_in[4];
    const float* Wa3 = (const float*)d_in[5];
    const float* ba3 = (const float*)d_in[6];
    const float* Wa4 = (const float*)d_in[7];
    const float* ba4 = (const float*)d_in[8];
    const float* Wa5 = (const float*)d_in[9];
    const float* ba5 = (const float*)d_in[10];
    const float* Wb1 = (const float*)d_in[11];
    const float* bb1 = (const float*)d_in[12];
    const float* Wb2 = (const float*)d_in[13];
    const float* bb2 = (const float*)d_in[14];
    const float* Wb3 = (const float*)d_in[15];
    const float* bb3 = (const float*)d_in[16];
    const float* Wb4 = (const float*)d_in[17];
    const float* bb4 = (const float*)d_in[18];
    const float* Wb5 = (const float*)d_in[19];
    const float* bb5 = (const float*)d_in[20];
    const float* Wb6 = (const float*)d_in[21];
    const float* bb6 = (const float*)d_in[22];

    prep_frags<<<dim3(NP), dim3(64), 0, stream>>>(
        Wa1, ba1, Wa2, ba2, Wa3, ba3, Wa4, ba4, Wa5, ba5,
        Wb1, bb1, Wb2, bb2, Wb3, bb3, Wb4, bb4, Wb5, bb5, Wb6, bb6);

    mlp_mfma<<<dim3(NROWS / 256 * NP), 256, 0, stream>>>(x, (float*)d_out);
}